// Round 9
// baseline (466.442 us; speedup 1.0000x reference)
//
#include <hip/hip_runtime.h>

#define BATCH   128
#define NUM_IN  4096
#define LVL     8
#define HID     32768
#define KH      32
#define OUTN    256
#define KOUT    64
#define SCALEA  4.9f

// Input u8 affine quantization range [-QR, QR]
#define QR      6.0f
#define QSTEP   (2.0f * QR / 255.0f)
#define INV255  (1.0f / 255.0f)
#define NT      (NUM_IN + LVL * HID)   // 266,240 nodes total
#define NSH     8                      // batch shards == XCDs

// Workspace layout:
//   in_bf @ 0         : bf16 inputs node-major packed pairs (level0 only). 1 MB
//   ext   @ 1,048,576 : u8 acts, XCD-SHARDED: shard s (= blockIdx%8 -> XCD s
//                       by round-robin dispatch) holds batch [16s,16s+16) for
//                       ALL nodes: ext[(s*NT + j)*8 + r] = ushort batch pair
//                       (elems s*16+2r, s*16+2r+1). 4.26 MB/shard ~ one XCD L2.
// R8 post-mortem: deep levels bound by random 128B fetches thrashing per-XCD
// L2 (34MB working set vs 4MB/XCD, ~2.2 TB/s beyond-L2). Sharding makes each
// XCD gather only from its own ~L2-sized shard.

__device__ __forceinline__ unsigned short f2bf(float f) {
    unsigned u = __float_as_uint(f);
    u += 0x7FFFu + ((u >> 16) & 1u);
    return (unsigned short)(u >> 16);
}
__device__ __forceinline__ float bf_lo(unsigned u) { return __uint_as_float(u << 16); }
__device__ __forceinline__ float bf_hi(unsigned u) { return __uint_as_float(u & 0xFFFF0000u); }

__device__ __forceinline__ unsigned q_in(float x) {   // input -> u8 in [-QR, QR]
    float t = (x + QR) * (255.0f / (2.0f * QR));
    t = fminf(fmaxf(t, 0.f), 255.f);
    return __float2uint_rn(t);
}

// ---------------------------------------------------------------------------
// Transpose x -> in_bf (bf16 pairs) + sharded u8 input rows in ext
// ---------------------------------------------------------------------------
__global__ __launch_bounds__(256) void transpose_x(const float* __restrict__ x,
                                                   unsigned* __restrict__ in_bf,
                                                   unsigned short* __restrict__ ext) {
    __shared__ float lds[64][129];
    const int n0 = blockIdx.x * 64;
    const int t  = threadIdx.x;
    #pragma unroll
    for (int it = 0; it < 32; ++it) {
        int i = it * 256 + t;
        int b = i >> 6;
        int n = i & 63;
        lds[n][b] = x[b * NUM_IN + n0 + n];
    }
    __syncthreads();
    #pragma unroll
    for (int it = 0; it < 16; ++it) {
        int i  = it * 256 + t;      // 64 nodes x 64 batch-pairs
        int n  = i >> 6;
        int bp = i & 63;
        float v0 = lds[n][2 * bp], v1 = lds[n][2 * bp + 1];
        in_bf[(n0 + n) * 64 + bp] = (unsigned)f2bf(v0) | ((unsigned)f2bf(v1) << 16);
        ext[((size_t)(bp >> 3) * NT + (n0 + n)) * 8 + (bp & 7)] =
            (unsigned short)(q_in(v0) | (q_in(v1) << 8));
    }
}

// ---------------------------------------------------------------------------
// Level 0: wave per unit, bf16 input gathers (full precision, 1 MB table);
// stores u8 act sharded (8 x 16B segments per wave).
// ---------------------------------------------------------------------------
__global__ __launch_bounds__(256) void level0(const unsigned* __restrict__ in_bf,
                                              unsigned short* __restrict__ ext,
                                              const int* __restrict__ idx,
                                              const float* __restrict__ w) {
    const int lane = threadIdx.x & 63;
    int h = (blockIdx.x << 2) + (threadIdx.x >> 6);
    h = __builtin_amdgcn_readfirstlane(h);
    const int*   ip = idx + h * KH;
    const float* wp = w   + h * KH;
    float ax = 0.f, ay = 0.f;
    #pragma unroll
    for (int k = 0; k < KH; ++k) {
        int   j  = __builtin_amdgcn_readfirstlane(ip[k]);
        float wk = wp[k];
        unsigned v = in_bf[(unsigned)j * 64 + lane];
        ax = fmaf(wk, bf_lo(v), ax);
        ay = fmaf(wk, bf_hi(v), ay);
    }
    unsigned qx = __float2uint_rn(255.f / (1.f + __expf(-SCALEA * ax)));
    unsigned qy = __float2uint_rn(255.f / (1.f + __expf(-SCALEA * ay)));
    ext[((size_t)(lane >> 3) * NT + (NUM_IN + h)) * 8 + (lane & 7)] =
        (unsigned short)(qx | (qy << 8));
}

// ---------------------------------------------------------------------------
// Levels 1..7, SHARDED: shard s = blockIdx&7 (-> XCD s). Wave = 8 units x
// 8 lanes; lane (g,r) handles unit g's batch pair r of shard s. One
// unconditional u8 gather per (unit,k) from the XCD-local 4.26 MB shard.
// idx/w loads are group-broadcast vector loads (L1-hit). Branchless.
// ---------------------------------------------------------------------------
__global__ __launch_bounds__(256) void deep_level(unsigned short* __restrict__ ext,
                                                  const int* __restrict__ idx,
                                                  const float* __restrict__ w,
                                                  int nbase) {  // NUM_IN + l*HID
    const int s    = blockIdx.x & 7;
    const int lane = threadIdx.x & 63;
    const int g    = lane >> 3, r = lane & 7;
    const int h    = (blockIdx.x >> 3) * 32 + (threadIdx.x >> 6) * 8 + g;
    unsigned short* sh = ext + (size_t)s * NT * 8;
    const int*   ip = idx + h * KH;
    const float* wp = w   + h * KH;

    float ax = 0.f, ay = 0.f, bias = 0.f;
    #pragma unroll
    for (int k = 0; k < KH; ++k) {
        int   j  = ip[k];                 // 8-lane group broadcast
        float wk = wp[k];
        unsigned t = sh[(unsigned)j * 8 + r];
        bool isin = (j < NUM_IN);
        float a = wk * (isin ? QSTEP : INV255);   // v_cndmask, no branch
        bias += isin ? (-QR * wk) : 0.f;
        ax = fmaf(a, (float)(t & 0xFFu), ax);
        ay = fmaf(a, (float)(t >> 8),   ay);
    }
    ax += bias;
    ay += bias;

    unsigned qx = __float2uint_rn(255.f / (1.f + __expf(-SCALEA * ax)));
    unsigned qy = __float2uint_rn(255.f / (1.f + __expf(-SCALEA * ay)));
    sh[(unsigned)(nbase + h) * 8 + r] = (unsigned short)(qx | (qy << 8));
}

// ---------------------------------------------------------------------------
// Output layer, sharded: task (s, o) on 8 lanes; f32 out[b][o].
// ---------------------------------------------------------------------------
__global__ __launch_bounds__(256) void output_layer(const unsigned short* __restrict__ ext,
                                                    const int* __restrict__ idx,
                                                    const float* __restrict__ w,
                                                    float* __restrict__ out) {
    const int s    = blockIdx.x & 7;
    const int lane = threadIdx.x & 63;
    const int g    = lane >> 3, r = lane & 7;
    const int o    = (blockIdx.x >> 3) * 32 + (threadIdx.x >> 6) * 8 + g;
    const unsigned short* sh = ext + (size_t)s * NT * 8;
    const int*   ip = idx + o * KOUT;
    const float* wp = w   + o * KOUT;

    float ax = 0.f, ay = 0.f, bias = 0.f;
    #pragma unroll
    for (int k = 0; k < KOUT; ++k) {
        int   j  = ip[k];
        float wk = wp[k];
        unsigned t = sh[(unsigned)j * 8 + r];
        bool isin = (j < NUM_IN);
        float a = wk * (isin ? QSTEP : INV255);
        bias += isin ? (-QR * wk) : 0.f;
        ax = fmaf(a, (float)(t & 0xFFu), ax);
        ay = fmaf(a, (float)(t >> 8),   ay);
    }
    ax += bias;
    ay += bias;
    int b0 = s * 16 + 2 * r;
    out[(b0 + 0) * OUTN + o] = 1.f / (1.f + __expf(-SCALEA * ax));
    out[(b0 + 1) * OUTN + o] = 1.f / (1.f + __expf(-SCALEA * ay));
}

extern "C" void kernel_launch(void* const* d_in, const int* in_sizes, int n_in,
                              void* d_out, int out_size, void* d_ws, size_t ws_size,
                              hipStream_t stream) {
    // setup_inputs() order: x, w_hidden, w_out, idx_hidden, idx_out
    const float* x          = (const float*)d_in[0];
    const float* w_hidden   = (const float*)d_in[1];
    const float* w_out      = (const float*)d_in[2];
    const int*   idx_hidden = (const int*)  d_in[3];
    const int*   idx_out    = (const int*)  d_in[4];
    float* out = (float*)d_out;

    char* ws = (char*)d_ws;
    unsigned*       in_bf = (unsigned*)      (ws + 0);        // 1,048,576 B
    unsigned short* ext   = (unsigned short*)(ws + 1048576);  // 8*266240*16 = 34,078,720 B

    transpose_x<<<NUM_IN / 64, 256, 0, stream>>>(x, in_bf, ext);

    level0<<<HID / 4, 256, 0, stream>>>(in_bf, ext, idx_hidden, w_hidden);
    for (int l = 1; l < LVL; ++l) {
        deep_level<<<(HID / 32) * NSH, 256, 0, stream>>>(
            ext,
            idx_hidden + (size_t)l * HID * KH,
            w_hidden   + (size_t)l * HID * KH,
            NUM_IN + l * HID);
    }
    output_layer<<<(OUTN / 32) * NSH, 256, 0, stream>>>(ext, idx_out, w_out, out);
}

// Round 10
// 269.355 us; speedup vs baseline: 1.7317x; 1.7317x over previous
//
#include <hip/hip_runtime.h>

#define BATCH   128
#define NUM_IN  4096
#define LVL     8
#define HID     32768
#define KH      32
#define OUTN    256
#define KOUT    64
#define SCALEA  4.9f

// Input u8 affine quantization range [-QR, QR]
#define QR      6.0f
#define QSTEP   (2.0f * QR / 255.0f)   // dequant scale
#define INV255  (1.0f / 255.0f)

// Workspace layout:
//   in_bf @ 0         : bf16 inputs node-major, packed pairs (uint per lane):
//                       in_bf[n*64 + lane] = batch {2lane, 2lane+1}.  1.0 MB
//   ext   @ 1,048,576 : u8 acts for ALL nodes j in [0, 4096+8*32768):
//                       j<4096  -> affine-quantized input  x ~ u*QSTEP - QR
//                       j>=4096 -> sigmoid act             s ~ u/255
//                       ext[j*64+lane] = ushort batch pair. 34.1 MB
//
// R9 post-mortem (locked): batch x bytes per node MUST be exactly one 128 B
// line gathered wave-uniform (u8 x 128 = 128 B). Sub-line sharding (R9)
// multiplies line-touches 8x and doubles FETCH. This is the R8 structure
// (265 us), which sits at the random-line service plateau:
// ~1M line-touches/level, ~50% L2 hit, fill path ~2.2 TB/s.

__device__ __forceinline__ unsigned short f2bf(float f) {
    unsigned u = __float_as_uint(f);
    u += 0x7FFFu + ((u >> 16) & 1u);   // round-to-nearest-even
    return (unsigned short)(u >> 16);
}
__device__ __forceinline__ float bf_lo(unsigned u) { return __uint_as_float(u << 16); }
__device__ __forceinline__ float bf_hi(unsigned u) { return __uint_as_float(u & 0xFFFF0000u); }

__device__ __forceinline__ unsigned q_in(float x) {   // input -> u8, range [-QR, QR]
    float t = (x + QR) * (255.0f / (2.0f * QR));
    t = fminf(fmaxf(t, 0.f), 255.f);
    return __float2uint_rn(t);
}

// ---------------------------------------------------------------------------
// Transpose x [B, NUM_IN] f32 -> in_bf (bf16 pairs) + ext[0..NUM_IN) (u8 pairs)
// ---------------------------------------------------------------------------
__global__ __launch_bounds__(256) void transpose_x(const float* __restrict__ x,
                                                   unsigned* __restrict__ in_bf,
                                                   unsigned short* __restrict__ ext) {
    __shared__ float lds[64][129];
    const int n0 = blockIdx.x * 64;
    const int t  = threadIdx.x;
    #pragma unroll
    for (int it = 0; it < 32; ++it) {
        int i = it * 256 + t;
        int b = i >> 6;
        int n = i & 63;
        lds[n][b] = x[b * NUM_IN + n0 + n];
    }
    __syncthreads();
    #pragma unroll
    for (int it = 0; it < 16; ++it) {
        int i  = it * 256 + t;      // 64 nodes x 64 batch-pairs
        int n  = i >> 6;
        int bp = i & 63;
        float v0 = lds[n][2 * bp], v1 = lds[n][2 * bp + 1];
        in_bf[(n0 + n) * 64 + bp] = (unsigned)f2bf(v0) | ((unsigned)f2bf(v1) << 16);
        ext[(unsigned)(n0 + n) * 64 + bp] =
            (unsigned short)(q_in(v0) | (q_in(v1) << 8));
    }
}

// ---------------------------------------------------------------------------
// Level 0: all sources are inputs (randint maxval = NUM_IN). bf16 gathers
// (256 B/node, 1 MB L2-resident table), full precision; writes u8 acts.
// ---------------------------------------------------------------------------
__global__ __launch_bounds__(256, 8) void level0(const unsigned* __restrict__ in_bf,
                                                 unsigned short* __restrict__ ext,
                                                 const int* __restrict__ idx,
                                                 const float* __restrict__ w) {
    const int lane = threadIdx.x & 63;
    int h = (blockIdx.x << 2) + (threadIdx.x >> 6);
    h = __builtin_amdgcn_readfirstlane(h);
    const int*   ip = idx + h * KH;
    const float* wp = w   + h * KH;
    float ax = 0.f, ay = 0.f;
    #pragma unroll
    for (int k = 0; k < KH; ++k) {
        int   j  = __builtin_amdgcn_readfirstlane(ip[k]);
        float wk = wp[k];
        unsigned v = in_bf[(unsigned)j * 64 + lane];
        ax = fmaf(wk, bf_lo(v), ax);
        ay = fmaf(wk, bf_hi(v), ay);
    }
    unsigned qx = __float2uint_rn(255.f / (1.f + __expf(-SCALEA * ax)));
    unsigned qy = __float2uint_rn(255.f / (1.f + __expf(-SCALEA * ay)));
    ext[(unsigned)(NUM_IN + h) * 64 + lane] = (unsigned short)(qx | (qy << 8));
}

// ---------------------------------------------------------------------------
// Levels 1..7: ONE unconditional u8 gather per entry (one full 128 B line,
// wave-uniform address) from the uniform ext table. Input-vs-hidden selects
// only scalar dequant coeffs:
//   input : wk*x = wk*QSTEP*u - QR*wk   hidden: wk*s = (wk/255)*u
// ---------------------------------------------------------------------------
__global__ __launch_bounds__(256, 8) void deep_level(unsigned short* __restrict__ ext,
                                                     const int* __restrict__ idx,
                                                     const float* __restrict__ w,
                                                     int nbase) {  // NUM_IN + l*HID
    const int lane = threadIdx.x & 63;
    int h = (blockIdx.x << 2) + (threadIdx.x >> 6);
    h = __builtin_amdgcn_readfirstlane(h);
    const int*   ip = idx + h * KH;
    const float* wp = w   + h * KH;

    float ax = 0.f, ay = 0.f, bias = 0.f;
    #pragma unroll
    for (int k = 0; k < KH; ++k) {
        int   j  = __builtin_amdgcn_readfirstlane(ip[k]);
        float wk = wp[k];
        bool isin = (j < NUM_IN);
        float a = wk * (isin ? QSTEP : INV255);   // scalar cselect
        bias   += isin ? (-QR * wk) : 0.f;        // scalar accumulate
        unsigned t = ext[(unsigned)j * 64 + lane];
        ax = fmaf(a, (float)(t & 0xFFu), ax);
        ay = fmaf(a, (float)(t >> 8),   ay);
    }
    ax += bias;
    ay += bias;

    unsigned qx = __float2uint_rn(255.f / (1.f + __expf(-SCALEA * ax)));
    unsigned qy = __float2uint_rn(255.f / (1.f + __expf(-SCALEA * ay)));
    ext[(unsigned)(nbase + h) * 64 + lane] = (unsigned short)(qx | (qy << 8));
}

// ---------------------------------------------------------------------------
// Output layer: same uniform-gather scheme, KO=64; f32 output out[b][o].
// ---------------------------------------------------------------------------
__global__ __launch_bounds__(256, 8) void output_layer(const unsigned short* __restrict__ ext,
                                                       const int* __restrict__ idx,
                                                       const float* __restrict__ w,
                                                       float* __restrict__ out) {
    const int lane = threadIdx.x & 63;
    int o = (blockIdx.x << 2) + (threadIdx.x >> 6);
    o = __builtin_amdgcn_readfirstlane(o);
    const int*   ip = idx + o * KOUT;
    const float* wp = w   + o * KOUT;

    float ax = 0.f, ay = 0.f, bias = 0.f;
    #pragma unroll
    for (int k = 0; k < KOUT; ++k) {
        int   j  = __builtin_amdgcn_readfirstlane(ip[k]);
        float wk = wp[k];
        bool isin = (j < NUM_IN);
        float a = wk * (isin ? QSTEP : INV255);
        bias   += isin ? (-QR * wk) : 0.f;
        unsigned t = ext[(unsigned)j * 64 + lane];
        ax = fmaf(a, (float)(t & 0xFFu), ax);
        ay = fmaf(a, (float)(t >> 8),   ay);
    }
    ax += bias;
    ay += bias;
    out[(2 * lane + 0) * OUTN + o] = 1.f / (1.f + __expf(-SCALEA * ax));
    out[(2 * lane + 1) * OUTN + o] = 1.f / (1.f + __expf(-SCALEA * ay));
}

extern "C" void kernel_launch(void* const* d_in, const int* in_sizes, int n_in,
                              void* d_out, int out_size, void* d_ws, size_t ws_size,
                              hipStream_t stream) {
    // setup_inputs() order: x, w_hidden, w_out, idx_hidden, idx_out
    const float* x          = (const float*)d_in[0];
    const float* w_hidden   = (const float*)d_in[1];
    const float* w_out      = (const float*)d_in[2];
    const int*   idx_hidden = (const int*)  d_in[3];
    const int*   idx_out    = (const int*)  d_in[4];
    float* out = (float*)d_out;

    char* ws = (char*)d_ws;
    unsigned*       in_bf = (unsigned*)      (ws + 0);        // 4096*64*4   = 1,048,576 B
    unsigned short* ext   = (unsigned short*)(ws + 1048576);  // 266,240*128 = 34,078,720 B

    transpose_x<<<NUM_IN / 64, 256, 0, stream>>>(x, in_bf, ext);

    level0<<<HID / 4, 256, 0, stream>>>(in_bf, ext, idx_hidden, w_hidden);
    for (int l = 1; l < LVL; ++l) {
        deep_level<<<HID / 4, 256, 0, stream>>>(
            ext,
            idx_hidden + (size_t)l * HID * KH,
            w_hidden   + (size_t)l * HID * KH,
            NUM_IN + l * HID);
    }
    output_layer<<<OUTN / 4, 256, 0, stream>>>(ext, idx_out, w_out, out);
}